// Round 4
// baseline (218.996 us; speedup 1.0000x reference)
//
#include <hip/hip_runtime.h>
#include <hip/hip_bf16.h>
#include <stdint.h>

typedef __bf16 bf16_t;
typedef __bf16 bf16x8 __attribute__((ext_vector_type(8)));
typedef float  f32x4  __attribute__((ext_vector_type(4)));

#define NGRAPH 128
#define NPG    512            // nodes per graph
#define CIN    512            // K dim
#define HID    256            // N dim of layer-1 GEMM
#define BM     64             // M tile per block (1024 blocks)
#define BK     64             // K tile

// async 16B global -> LDS (wave-uniform base + lane*16 ordering required)
__device__ __forceinline__ void gl2lds16(const void* g, void* l) {
  __builtin_amdgcn_global_load_lds(
      (const __attribute__((address_space(1))) uint32_t*)g,
      (__attribute__((address_space(3))) uint32_t*)l, 16, 0, 0);
}

// ---------------------------------------------------------------------------
// Prep: W1 [8][512][256] f32 -> Bfrag: pre-built MFMA B fragments, bf16.
// Layout: [h][kt][w][f][lane] * 8 bf16, f = ni*2 + ks2 (ni: 16-col group of
// wave w's 64-col slice; ks2: K-half of the 64-K tile). Lane (q=lane>>4,
// t=lane&15) holds B[k = ks2*32 + q*8 + j][n = w*64 + ni*16 + t], j=0..7.
// Main then loads each fragment as one fully-coalesced 1 KB global_load_dwordx4
// straight into VGPRs (no LDS, no ds_read, L2-resident).
// ---------------------------------------------------------------------------
__global__ __launch_bounds__(256) void prep_w1(const float* __restrict__ W1,
                                               bf16_t* __restrict__ Bfrag) {
  __shared__ float tile[64][65];          // [k][n], +1 pad
  const int kt = blockIdx.x;              // 8 K-tiles
  const int h  = blockIdx.y;              // 8 heads
  const int tid = threadIdx.x;
  const int kr = tid >> 4, n4 = tid & 15;
  for (int w = 0; w < 4; w++) {           // 64-col slice = wave w's slice
    if (w) __syncthreads();
    const float* src = W1 + (((size_t)h * CIN + kt * 64) * HID + w * 64);
#pragma unroll
    for (int i = 0; i < 4; i++) {
      const int k = kr + i * 16;
      const float4 v = *(const float4*)(src + (size_t)k * HID + n4 * 4);
      tile[k][n4 * 4 + 0] = v.x; tile[k][n4 * 4 + 1] = v.y;
      tile[k][n4 * 4 + 2] = v.z; tile[k][n4 * 4 + 3] = v.w;
    }
    __syncthreads();
    bf16_t* dst = Bfrag + (size_t)(((h * 8 + kt) * 4 + w)) * 4096;
#pragma unroll
    for (int e = 0; e < 2; e++) {
      const int idx = tid * 2 + e;        // 0..511 = f(8) x lane(64)
      const int f = idx >> 6, lane = idx & 63;
      const int ni = f >> 1, ks2 = f & 1;
      const int q = lane >> 4, t = lane & 15;
      bf16x8 o;
#pragma unroll
      for (int j = 0; j < 8; j++)
        o[j] = (bf16_t)tile[ks2 * 32 + q * 8 + j][ni * 16 + t];
      *(bf16x8*)(dst + (size_t)(f * 64 + lane) * 8) = o;
    }
  }
}

// ---------------------------------------------------------------------------
// Main fused kernel: block = 64-node slice of one graph (1024 blocks).
// 4 waves partition HID into 64-wide slices; per wave: 4(mi) x 4(ni) tiles of
// 16x16x32 bf16 MFMA. A staged raw fp32 via global_load_lds (4 DMA issues per
// ktile, XOR-swizzled), converted fp32->bf16 at fragment-load. B loaded
// directly global->VGPR from pre-built fragments (coalesced, L2-hot) — no LDS,
// no barrier dependency. K-loop phase-staggered per block so co-resident
// blocks' barrier drains overlap other blocks' compute.
// LDS = 16K (A) + 1K (red) = 17 KB -> VGPR-capped occupancy, 4 blocks/CU.
// ---------------------------------------------------------------------------
__global__ __launch_bounds__(256, 4) void energy_main(
    const float* __restrict__ x, const int* __restrict__ task,
    const bf16_t* __restrict__ Bfrag, const float* __restrict__ b1,
    const float* __restrict__ W2, const float* __restrict__ b2,
    float* __restrict__ out) {
  __shared__ float As[BM * BK];           // 16 KB, swizzled fp32 image
  __shared__ float red[4][BM];            // 1 KB

  const int bx   = blockIdx.x;
  const int g    = bx >> 3;               // graph
  const int mt   = bx & 7;                // M-tile within graph
  const int head = task[g];
  const int base = g * NPG + mt * BM;
  const int tid  = threadIdx.x;
  const int wave = tid >> 6, lane = tid & 63;
  const int q = lane >> 4, t = lane & 15;

  const float*  Ag = x + (size_t)base * CIN;
  const bf16_t* Bw = Bfrag + (size_t)(head * 32 + wave) * 4096;

  const int a_row16 = tid >> 4;           // row = j*16 + a_row16
  const int a_cp    = tid & 15;           // slot chunk (16 B)
  const int phase   = (bx * 5 + (bx >> 8)) & 7;   // de-phase co-resident blocks

  f32x4 acc[4][4] = {};

  for (int kk = 0; kk < 8; kk++) {
    const int kt = (kk + phase) & 7;
    const int k0 = kt * 64;
    if (kk) __syncthreads();              // prior MFMA reads of As done
    // ---- A: 4 async DMA issues, 4 KB each (raw fp32, swizzled chunks)
#pragma unroll
    for (int j = 0; j < 4; j++) {
      const int row = j * 16 + a_row16;
      const int c = a_cp ^ (row & 7);     // data chunk for this slot
      gl2lds16(Ag + (size_t)row * CIN + k0 + c * 4, As + j * 1024 + tid * 4);
    }
    // ---- B: 8 fragments straight to VGPR (1 KB coalesced each, L2-hot)
    const bf16_t* Bt = Bw + (size_t)kt * 16384;
    bf16x8 bfr[8];
#pragma unroll
    for (int f = 0; f < 8; f++)
      bfr[f] = *(const bf16x8*)(Bt + (size_t)f * 512 + lane * 8);
    __syncthreads();                      // drains A-DMA (vmcnt)

#pragma unroll
    for (int ks2 = 0; ks2 < 2; ks2++) {
#pragma unroll
      for (int mi = 0; mi < 4; mi++) {
        const int row = mi * 16 + t;
        const int s = row & 7;
        const int c0 = ks2 * 8 + q * 2;   // even chunk index
        const float4 v0 = *(const float4*)(As + row * 64 + ((c0) ^ s) * 4);
        const float4 v1 = *(const float4*)(As + row * 64 + ((c0 + 1) ^ s) * 4);
        bf16x8 af;
        af[0] = (bf16_t)v0.x; af[1] = (bf16_t)v0.y;
        af[2] = (bf16_t)v0.z; af[3] = (bf16_t)v0.w;
        af[4] = (bf16_t)v1.x; af[5] = (bf16_t)v1.y;
        af[6] = (bf16_t)v1.z; af[7] = (bf16_t)v1.w;
#pragma unroll
        for (int ni = 0; ni < 4; ni++)
          acc[mi][ni] = __builtin_amdgcn_mfma_f32_16x16x32_bf16(
              af, bfr[ni * 2 + ks2], acc[mi][ni], 0, 0, 0);
      }
    }
  }

  // ---- fused epilogue: y = silu(acc + b1) . W2 + b2
  // C/D layout: col(n) = t (+tiles), row(m) = q*4 + r (+mi*16)
  float w2c[4], b1c[4];
#pragma unroll
  for (int ni = 0; ni < 4; ni++) {
    const int col = wave * 64 + ni * 16 + t;
    w2c[ni] = W2[head * HID + col];
    b1c[ni] = b1[head * HID + col];
  }
  float part[4][4];
#pragma unroll
  for (int mi = 0; mi < 4; mi++)
#pragma unroll
    for (int r = 0; r < 4; r++) {
      float sacc = 0.f;
#pragma unroll
      for (int ni = 0; ni < 4; ni++) {
        const float hh = acc[mi][ni][r] + b1c[ni];
        sacc += (hh / (1.f + __expf(-hh))) * w2c[ni];   // silu * w2
      }
      part[mi][r] = sacc;
    }
#pragma unroll
  for (int off = 1; off < 16; off <<= 1)
#pragma unroll
    for (int mi = 0; mi < 4; mi++)
#pragma unroll
      for (int r = 0; r < 4; r++)
        part[mi][r] += __shfl_xor(part[mi][r], off, 64);
  if (t == 0) {
#pragma unroll
    for (int mi = 0; mi < 4; mi++)
#pragma unroll
      for (int r = 0; r < 4; r++)
        red[wave][mi * 16 + q * 4 + r] = part[mi][r];
  }
  __syncthreads();
  if (tid < BM) {
    out[base + tid] = red[0][tid] + red[1][tid] + red[2][tid] + red[3][tid] +
                      b2[head];
  }
}

extern "C" void kernel_launch(void* const* d_in, const int* in_sizes, int n_in,
                              void* d_out, int out_size, void* d_ws,
                              size_t ws_size, hipStream_t stream) {
  const float* x    = (const float*)d_in[0];   // [65536,512] f32
  // d_in[1] = n_node (all 512): fixed 512-node graphs
  const int*   task = (const int*)d_in[2];     // [128] i32
  const float* W1   = (const float*)d_in[3];   // [8,512,256] f32
  const float* b1   = (const float*)d_in[4];   // [8,256] f32
  const float* W2   = (const float*)d_in[5];   // [8,256,1] f32
  const float* b2   = (const float*)d_in[6];   // [8,1] f32
  float* out = (float*)d_out;                  // [65536] f32

  bf16_t* Bfrag = (bf16_t*)d_ws;               // 2 MB pre-built B fragments

  prep_w1<<<dim3(8, 8), 256, 0, stream>>>(W1, Bfrag);
  energy_main<<<dim3(NGRAPH * 8), 256, 0, stream>>>(x, task, Bfrag, b1, W2, b2,
                                                    out);
}

// Round 5
// 214.285 us; speedup vs baseline: 1.0220x; 1.0220x over previous
//
#include <hip/hip_runtime.h>
#include <hip/hip_bf16.h>
#include <stdint.h>

typedef __bf16 bf16_t;
typedef __bf16 bf16x8 __attribute__((ext_vector_type(8)));
typedef float  f32x4  __attribute__((ext_vector_type(4)));

#define NGRAPH 128
#define NPG    512            // nodes per graph
#define CIN    512            // K dim
#define HID    256            // N dim of layer-1 GEMM
#define BM     128            // M tile per block
#define BK     64             // K tile

// async 16B global -> LDS (wave-uniform base + lane*16 ordering required)
__device__ __forceinline__ void gl2lds16(const void* g, void* l) {
  __builtin_amdgcn_global_load_lds(
      (const __attribute__((address_space(1))) uint32_t*)g,
      (__attribute__((address_space(3))) uint32_t*)l, 16, 0, 0);
}

// ---------------------------------------------------------------------------
// Prep: W1 [8][512][256] f32 -> Bimg: per (head, ktile) a 32 KB LDS-image of
// the 256(n) x 64(k) bf16 B-tile, XOR-swizzled: slot (n, c') holds k-chunk
// c = c' ^ (n&7) (8 bf16 each). Main kernel then stages B with pure-linear
// global_load_lds and gets conflict-free (<=2-way) ds_read_b128 fragments.
// ---------------------------------------------------------------------------
__global__ __launch_bounds__(256) void prep_w1(const float* __restrict__ W1,
                                               bf16_t* __restrict__ Bimg) {
  __shared__ float tile[64][65];          // [k][n], +1 pad
  const int n0 = blockIdx.x * 64;         // 4 tiles over HID
  const int kt = blockIdx.y;              // 8 tiles over CIN
  const int h  = blockIdx.z;              // 8 heads
  const int k0 = kt * 64;
  const int tid = threadIdx.x;
  const int r = tid >> 4, c4 = tid & 15;
  const float* src = W1 + (((size_t)h * CIN + k0) * HID + n0);
#pragma unroll
  for (int i = 0; i < 4; i++) {
    const int rr = r + i * 16;
    const float4 v = *(const float4*)(src + (size_t)rr * HID + c4 * 4);
    tile[rr][c4 * 4 + 0] = v.x; tile[rr][c4 * 4 + 1] = v.y;
    tile[rr][c4 * 4 + 2] = v.z; tile[rr][c4 * 4 + 3] = v.w;
  }
  __syncthreads();
  bf16_t* dst = Bimg + (size_t)(h * 8 + kt) * 16384;
#pragma unroll
  for (int i = 0; i < 2; i++) {
    const int u = tid + i * 256;
    const int n = u >> 3, c = u & 7;      // n within tile, data k-chunk c
    bf16x8 o;
#pragma unroll
    for (int j = 0; j < 8; j++) o[j] = (bf16_t)tile[c * 8 + j][n];
    const int ng = n0 + n;
    const int cp = c ^ (ng & 7);          // swizzled slot
    *(bf16x8*)(dst + (size_t)ng * 64 + cp * 8) = o;
  }
}

// ---------------------------------------------------------------------------
// Main fused kernel: block = 128-node slice of one graph (512 blocks).
// 4 waves partition HID into 64-wide slices; per wave: 8(mi) x 4(ni) tiles of
// 16x16x32 bf16 MFMA. A staged raw fp32 via global_load_lds (XOR-swizzled
// source chunks), converted fp32->bf16 at fragment-load. B staged linear from
// the pre-swizzled image (L2-resident). Epilogue fuses bias+SiLU+dot(W2)+b2.
// HBM-supply-limited: compulsory 134 MB x-read = 21.5 us floor.
// ---------------------------------------------------------------------------
__global__ __launch_bounds__(256, 2) void energy_main(
    const float* __restrict__ x, const int* __restrict__ task,
    const bf16_t* __restrict__ Bimg, const float* __restrict__ b1,
    const float* __restrict__ W2, const float* __restrict__ b2,
    float* __restrict__ out) {
  __shared__ float  As[BM * BK];          // 32 KB, swizzled fp32 image
  __shared__ bf16_t Bs[HID * BK];         // 32 KB, swizzled bf16 image
  __shared__ float  red[4][BM];           // 2 KB

  const int bx   = blockIdx.x;
  const int g    = bx >> 2;               // graph
  const int mt   = bx & 3;                // M-tile within graph
  const int head = task[g];
  const int base = g * NPG + mt * BM;
  const int tid  = threadIdx.x;
  const int wave = tid >> 6, lane = tid & 63;
  const int q = lane >> 4, t = lane & 15;

  const float*  Ag = x + (size_t)base * CIN;
  const bf16_t* Bh = Bimg + (size_t)head * 8 * 16384;

  const int a_row16 = tid >> 4;           // row = j*16 + a_row16
  const int a_cp    = tid & 15;           // slot chunk (16 B)

  f32x4 acc[8][4] = {};

  for (int kt = 0; kt < 8; kt++) {
    const int k0 = kt * 64;
    if (kt) __syncthreads();              // prior MFMA reads done
    // ---- A: 8 async issues, 4 KB each (raw fp32, swizzled source chunk)
#pragma unroll
    for (int j = 0; j < 8; j++) {
      const int row = j * 16 + a_row16;
      const int c = a_cp ^ (row & 7);     // data chunk for this slot
      gl2lds16(Ag + (size_t)row * CIN + k0 + c * 4, As + j * 1024 + tid * 4);
    }
    // ---- B: 8 async issues, pure linear copy of pre-swizzled image
    const bf16_t* Bt = Bh + (size_t)kt * 16384;
#pragma unroll
    for (int j = 0; j < 8; j++)
      gl2lds16(Bt + j * 2048 + tid * 8, Bs + j * 2048 + tid * 8);
    __syncthreads();                      // drains vmcnt (loads landed)

#pragma unroll
    for (int ks = 0; ks < 64; ks += 32) {
      bf16x8 bfr[4];
#pragma unroll
      for (int ni = 0; ni < 4; ni++) {
        const int n = wave * 64 + ni * 16 + t;
        const int cp = (ks / 8 + q) ^ (n & 7);
        bfr[ni] = *(const bf16x8*)(Bs + n * 64 + cp * 8);
      }
#pragma unroll
      for (int mi = 0; mi < 8; mi++) {
        const int row = mi * 16 + t;
        const int s = row & 7;
        const int c0 = ks / 4 + q * 2;    // even chunk index
        const float4 v0 = *(const float4*)(As + row * 64 + ((c0) ^ s) * 4);
        const float4 v1 = *(const float4*)(As + row * 64 + ((c0 + 1) ^ s) * 4);
        bf16x8 af;
        af[0] = (bf16_t)v0.x; af[1] = (bf16_t)v0.y;
        af[2] = (bf16_t)v0.z; af[3] = (bf16_t)v0.w;
        af[4] = (bf16_t)v1.x; af[5] = (bf16_t)v1.y;
        af[6] = (bf16_t)v1.z; af[7] = (bf16_t)v1.w;
#pragma unroll
        for (int ni = 0; ni < 4; ni++)
          acc[mi][ni] = __builtin_amdgcn_mfma_f32_16x16x32_bf16(
              af, bfr[ni], acc[mi][ni], 0, 0, 0);
      }
    }
  }

  // ---- fused epilogue: y = silu(acc + b1) . W2 + b2
  // C/D layout: col(n) = t (+tiles), row(m) = q*4 + r (+mi*16)
  float w2c[4], b1c[4];
#pragma unroll
  for (int ni = 0; ni < 4; ni++) {
    const int col = wave * 64 + ni * 16 + t;
    w2c[ni] = W2[head * HID + col];
    b1c[ni] = b1[head * HID + col];
  }
  float part[8][4];
#pragma unroll
  for (int mi = 0; mi < 8; mi++)
#pragma unroll
    for (int r = 0; r < 4; r++) {
      float sacc = 0.f;
#pragma unroll
      for (int ni = 0; ni < 4; ni++) {
        const float hh = acc[mi][ni][r] + b1c[ni];
        sacc += (hh / (1.f + __expf(-hh))) * w2c[ni];   // silu * w2
      }
      part[mi][r] = sacc;
    }
#pragma unroll
  for (int off = 1; off < 16; off <<= 1)
#pragma unroll
    for (int mi = 0; mi < 8; mi++)
#pragma unroll
      for (int r = 0; r < 4; r++)
        part[mi][r] += __shfl_xor(part[mi][r], off, 64);
  if (t == 0) {
#pragma unroll
    for (int mi = 0; mi < 8; mi++)
#pragma unroll
      for (int r = 0; r < 4; r++)
        red[wave][mi * 16 + q * 4 + r] = part[mi][r];
  }
  __syncthreads();
  if (tid < BM) {
    out[base + tid] = red[0][tid] + red[1][tid] + red[2][tid] + red[3][tid] +
                      b2[head];
  }
}

extern "C" void kernel_launch(void* const* d_in, const int* in_sizes, int n_in,
                              void* d_out, int out_size, void* d_ws,
                              size_t ws_size, hipStream_t stream) {
  const float* x    = (const float*)d_in[0];   // [65536,512] f32
  // d_in[1] = n_node (all 512): fixed 512-node graphs
  const int*   task = (const int*)d_in[2];     // [128] i32
  const float* W1   = (const float*)d_in[3];   // [8,512,256] f32
  const float* b1   = (const float*)d_in[4];   // [8,256] f32
  const float* W2   = (const float*)d_in[5];   // [8,256,1] f32
  const float* b2   = (const float*)d_in[6];   // [8,1] f32
  float* out = (float*)d_out;                  // [65536] f32

  bf16_t* Bimg = (bf16_t*)d_ws;                // 2 MB swizzled W1 image

  prep_w1<<<dim3(4, 8, 8), 256, 0, stream>>>(W1, Bimg);
  energy_main<<<dim3(NGRAPH * 4), 256, 0, stream>>>(x, task, Bimg, b1, W2, b2,
                                                    out);
}